// Round 9
// baseline (379.423 us; speedup 1.0000x reference)
//
#include <hip/hip_runtime.h>
#include <math.h>

// ---------------------------------------------------------------------------
// Fastformer encoder layer — Round 16 (= R15 resubmitted; container infra
// failure last round, no measurement taken).
//
// R15 rationale (unchanged): session audit shows R9 (346.6 us) is the best
// total; R10-R14 schedule variants all pinned at 36-40% MfmaUtil. This build
// = R9 verbatim core + two since-validated component swaps:
//  * kv + lin1: R9 fgemm2 (512 thr, 256-row tile, B through LDS, counted
//    vmcnt over gl2lds-only VMEM stream — R9-validated, absmax 0.0156).
//  * out + lin2: R13 fgemm5 BM=128 (B direct-to-reg fragment-linear, 32 KB
//    LDS -> 3 blocks/CU, full __syncthreads) replacing R9's 96KB/1-CU
//    BN=128 variant.
//  * weights: wkv/l1 row-major stream cast (R9); wo/l2 fragment-linear via
//    coalesced-read formula (R14-validated). No XCD swizzle (R14: -36% FETCH
//    regression for these B-reuse-dominant shapes).
// ws: h16@0 | kv16/act16@16M | vq@48M | wkv16@64M | l116@68M | wo_sw@76M |
//     l2_sw@78M | gk@82M | attn partials@83M
// ---------------------------------------------------------------------------

#define DM     1024
#define FFH    2048
#define M_TOT  8192

typedef _Float16 f16x8 __attribute__((ext_vector_type(8)));
typedef float    f32x4 __attribute__((ext_vector_type(4)));

__device__ __forceinline__ void gl2lds16(const void* g, void* l) {
    __builtin_amdgcn_global_load_lds(
        (const __attribute__((address_space(1))) void*)g,
        (__attribute__((address_space(3))) void*)l, 16, 0, 0);
}
__device__ __forceinline__ unsigned short f2h(float x) {
    union { _Float16 h; unsigned short u; } c;
    c.h = (_Float16)x;
    return c.u;
}
__device__ __forceinline__ float h2f(unsigned short u) {
    union { unsigned short u; _Float16 h; } c;
    c.u = u;
    return (float)c.h;
}

// ---------------------------------------------------------------------------
// weight cast fp32 -> fp16. Ranges 0,1: row-major stream (dst chunk = i).
// Ranges 2,3: fragment-linear, coalesced reads (R14-validated formula):
//   row=i>>rsh, c=i&cmk, kt=c>>2, qq=c&3;
//   dch=((row>>4)*KT+kt)*64+qq*16+(row&15).
// ---------------------------------------------------------------------------
__global__ __launch_bounds__(256) void wcast2(
    const float* __restrict__ s0, const float* __restrict__ s1,
    const float* __restrict__ s2, const float* __restrict__ s3,
    unsigned short* __restrict__ d0, unsigned short* __restrict__ d1,
    unsigned short* __restrict__ d2, unsigned short* __restrict__ d3)
{
    int i = blockIdx.x * 256 + threadIdx.x;
    const float* s; unsigned short* d;
    bool frag = false; int rsh = 0, cmk = 0, KT = 0;
    if      (i < 262144) {               s = s0; d = d0; }                     // wkv row-major
    else if (i < 786432) { i -= 262144;  s = s1; d = d1; }                     // l1  row-major
    else if (i < 917504) { i -= 786432;  s = s2; d = d2; frag = true; rsh = 7; cmk = 127; KT = 32; }   // wo
    else                 { i -= 917504;  s = s3; d = d3; frag = true; rsh = 8; cmk = 255; KT = 64; }   // l2
    const float4 v0 = ((const float4*)(s + (size_t)i * 8))[0];
    const float4 v1 = ((const float4*)(s + (size_t)i * 8))[1];
    ushort4 h0, h1;
    h0.x = f2h(v0.x); h0.y = f2h(v0.y); h0.z = f2h(v0.z); h0.w = f2h(v0.w);
    h1.x = f2h(v1.x); h1.y = f2h(v1.y); h1.z = f2h(v1.z); h1.w = f2h(v1.w);
    size_t dch = i;
    if (frag) {
        const int row = i >> rsh, c = i & cmk;
        const int kt  = c >> 2,  qq = c & 3;
        dch = ((size_t)(row >> 4) * KT + kt) * 64 + qq * 16 + (row & 15);
    }
    unsigned short* dst = d + dch * 8;
    *(ushort4*)dst       = h0;
    *(ushort4*)(dst + 4) = h1;
}

// ---------------------------------------------------------------------------
// LayerNorm -> fp16. One block/row, one float4/thread.
// ---------------------------------------------------------------------------
__global__ __launch_bounds__(256) void ln_f16(
    const float* __restrict__ x, const float* __restrict__ g,
    const float* __restrict__ b, unsigned short* __restrict__ y)
{
    const int row = blockIdx.x;
    const int t   = threadIdx.x;
    const float4 v = ((const float4*)(x + (size_t)row * DM))[t];

    float s  = v.x + v.y + v.z + v.w;
    float ss = v.x * v.x + v.y * v.y + v.z * v.z + v.w * v.w;
    #pragma unroll
    for (int off = 32; off > 0; off >>= 1) {
        s  += __shfl_xor(s, off);
        ss += __shfl_xor(ss, off);
    }
    __shared__ float sm[8];
    const int wave = t >> 6;
    if ((t & 63) == 0) { sm[wave * 2] = s; sm[wave * 2 + 1] = ss; }
    __syncthreads();
    s  = sm[0] + sm[2] + sm[4] + sm[6];
    ss = sm[1] + sm[3] + sm[5] + sm[7];

    const float mu  = s * (1.0f / DM);
    const float var = ss * (1.0f / DM) - mu * mu;
    const float r   = rsqrtf(var + 1e-5f);

    const float4 gv = ((const float4*)g)[t];
    const float4 bv = ((const float4*)b)[t];
    ushort4 o;
    o.x = f2h((v.x - mu) * r * gv.x + bv.x);
    o.y = f2h((v.y - mu) * r * gv.y + bv.y);
    o.z = f2h((v.z - mu) * r * gv.z + bv.z);
    o.w = f2h((v.w - mu) * r * gv.w + bv.w);
    ((ushort4*)(y + (size_t)row * DM))[t] = o;
}

// ---------------------------------------------------------------------------
// attention partial pass + merge (verified R4-R14, unchanged).
// ---------------------------------------------------------------------------
__global__ __launch_bounds__(256) void attn_part(
    const unsigned short* __restrict__ kv, const float* __restrict__ kw,
    float* __restrict__ pm, float* __restrict__ pl, float* __restrict__ ps)
{
    const int blk = blockIdx.x;
    const int bh = blk >> 2, qt = blk & 3;
    const int b = bh >> 4, h = bh & 15;
    const int t = threadIdx.x, e = t & 63, w = t >> 6;
    const int nbase = qt * 256 + w * 64;
    const unsigned short* kp =
        kv + (size_t)b * 1024 * 2048 + (size_t)nbase * 2048 + h * 64 + e;
    const float* kwr = kw + h * 1024 + nbase;

    float m = -1e30f, l = 0.f, s = 0.f;
    #pragma unroll 4
    for (int i = 0; i < 64; ++i) {
        const float kval = h2f(kp[(size_t)i * 2048]);
        const float x    = kval * kwr[i] * 0.125f;
        const float nm   = fmaxf(m, x);
        const float c    = __expf(m - nm);
        const float ex   = __expf(x - nm);
        l = l * c + ex;
        s = s * c + ex * kval;
        m = nm;
    }
    __shared__ float sm[3][256];
    sm[0][t] = m; sm[1][t] = l; sm[2][t] = s;
    __syncthreads();
    if (t < 64) {
        #pragma unroll
        for (int ww = 1; ww < 4; ++ww) {
            const float m2 = sm[0][ww * 64 + e];
            const float l2 = sm[1][ww * 64 + e];
            const float s2 = sm[2][ww * 64 + e];
            const float nm = fmaxf(m, m2);
            const float c1 = __expf(m - nm);
            const float c2 = __expf(m2 - nm);
            l = l * c1 + l2 * c2;
            s = s * c1 + s2 * c2;
            m = nm;
        }
        const int o = blk * 64 + e;
        pm[o] = m; pl[o] = l; ps[o] = s;
    }
}

__global__ __launch_bounds__(64) void attn_merge(
    const float* __restrict__ pm, const float* __restrict__ pl,
    const float* __restrict__ ps, float* __restrict__ gk)
{
    const int bh = blockIdx.x, e = threadIdx.x;
    const int b = bh >> 4, h = bh & 15;
    int o = bh * 4 * 64 + e;
    float m = pm[o], l = pl[o], s = ps[o];
    #pragma unroll
    for (int qt = 1; qt < 4; ++qt) {
        o += 64;
        const float m2 = pm[o], l2 = pl[o], s2 = ps[o];
        const float nm = fmaxf(m, m2);
        const float c1 = __expf(m - nm);
        const float c2 = __expf(m2 - nm);
        l = l * c1 + l2 * c2;
        s = s * c1 + s2 * c2;
        m = nm;
    }
    gk[(size_t)b * DM + h * 64 + e] = s / l;
}

// ---------------------------------------------------------------------------
// v-scale: vq[m][d] = fp16( v16[m][d] * gk[batch][d] ).
// ---------------------------------------------------------------------------
__global__ __launch_bounds__(256) void vscale_f16(
    const unsigned short* __restrict__ kv, const float* __restrict__ gk,
    unsigned short* __restrict__ vq)
{
    const int m = blockIdx.x;
    const int t = threadIdx.x;
    const int b = m >> 10;
    const ushort4 v4 = *(const ushort4*)(kv + (size_t)m * 2048 + 1024 + t * 4);
    const float4  s4 = *(const float4*)(gk + b * DM + t * 4);
    ushort4 o;
    o.x = f2h(h2f(v4.x) * s4.x);
    o.y = f2h(h2f(v4.y) * s4.y);
    o.z = f2h(h2f(v4.z) * s4.z);
    o.w = f2h(h2f(v4.w) * s4.w);
    *(ushort4*)(vq + (size_t)m * DM + t * 4) = o;
}

// ---------------------------------------------------------------------------
// fgemm2 — R9-validated 512-thr GEMM (kv + lin1). 8 waves (2x4), 256-row
// tile, BN=256, per-wave 128x64, acc[8][4]. A,B staged via gl2lds into
// 128KB LDS (validated 128B-row XOR layout). Counted vmcnt over the
// gl2lds-only VMEM stream (safe: no compiler-tracked register loads in
// the window — R12 lesson). LIN1ACT: B rows = {a: n0..+127, g: FFH+n0..};
// epilogue fuses a*relu(g) via LDS xch.
// ---------------------------------------------------------------------------
template <bool LIN1ACT, int OUTM, int BN, int WM>
__global__ __launch_bounds__(512, 2) void fgemm2(
    const unsigned short* __restrict__ A,
    const unsigned short* __restrict__ W,
    const float* __restrict__ bias,
    const float* __restrict__ residual,
    float* __restrict__ Cf, unsigned short* __restrict__ Cq,
    int K, int lda, int ldc)
{
    constexpr int WN    = 8 / WM;
    constexpr int WROWS = 256 / WM;
    constexpr int WCOLS = BN / WN;
    constexpr int MR    = WROWS / 16;
    constexpr int NR    = WCOLS / 16;
    static_assert(NR == 4, "NR must be 4");
    constexpr int NBJ   = BN / 64;
    constexpr int ABUF  = 32768;
    constexpr int BBUF  = BN * 128;
    constexpr int BBASE = 2 * ABUF;

    __shared__ __align__(16) char lds[BBASE + 2 * BBUF];

    const int t   = threadIdx.x;
    const int wid = t >> 6, L = t & 63;
    const int wm  = wid % WM, wn = wid / WM;
    const int fr  = L & 15,  q  = L >> 4;
    const int m0  = blockIdx.y * 256;
    const int n0  = blockIdx.x * (LIN1ACT ? 128 : BN);

    const int srow = t >> 3;
    const int sch  = (t & 7) ^ (srow & 7);
    const unsigned short* pA  = A + (size_t)(m0 + srow) * lda + sch * 8;
    const unsigned short* pBs = W + (size_t)srow * K + sch * 8;
    size_t bro[4];
    #pragma unroll
    for (int j = 0; j < NBJ; ++j) {
        const int br = LIN1ACT ? ((j < 2) ? (n0 + 64 * j)
                                          : (FFH + n0 + 64 * (j - 2)))
                               : (n0 + 64 * j);
        bro[j] = (size_t)br * K;
    }

    int aoff[MR], boff[NR];
    #pragma unroll
    for (int mi = 0; mi < MR; ++mi) {
        const int row = wm * WROWS + mi * 16 + fr;
        aoff[mi] = row * 128 + ((q ^ (row & 7)) << 4);
    }
    #pragma unroll
    for (int ni = 0; ni < NR; ++ni) {
        const int col = wn * WCOLS + ni * 16 + fr;
        boff[ni] = BBASE + col * 128 + ((q ^ (col & 7)) << 4);
    }

    f32x4 acc[MR][NR];
    #pragma unroll
    for (int i = 0; i < MR; ++i)
        #pragma unroll
        for (int j = 0; j < NR; ++j) acc[i][j] = (f32x4){0.f, 0.f, 0.f, 0.f};

#define STGA(par, j, koff) gl2lds16(pA + (size_t)(j) * 64 * lda + (koff),     \
                                    lds + (par) * ABUF + t * 16 + (j) * 8192)
#define STGB(par, j, koff) gl2lds16(pBs + bro[j] + (koff),                    \
                                    lds + BBASE + (par) * BBUF + t * 16 +     \
                                    (j) * 8192)
#define LDB(ks) {                                                             \
    _Pragma("unroll")                                                         \
    for (int ni = 0; ni < 4; ++ni)                                            \
        bv[ni] = *(const f16x8*)(bbase + (boff[ni] ^ ((ks) * 64))); }
#define LDA4(mh, ks) {                                                        \
    _Pragma("unroll")                                                         \
    for (int r = 0; r < 4; ++r)                                               \
        av[r] = *(const f16x8*)(abase + (aoff[(mh) * 4 + r] ^ ((ks) * 64))); }
#define FMA16(mh) {                                                           \
    __builtin_amdgcn_s_setprio(1);                                            \
    _Pragma("unroll")                                                         \
    for (int r = 0; r < 4; ++r)                                               \
        _Pragma("unroll")                                                     \
        for (int ni = 0; ni < 4; ++ni)                                        \
            acc[(mh) * 4 + r][ni] = __builtin_amdgcn_mfma_f32_16x16x32_f16(   \
                av[r], bv[ni], acc[(mh) * 4 + r][ni], 0, 0, 0);               \
    __builtin_amdgcn_s_setprio(0); }

    // prologue: full tile 0 into parity 0
    STGA(0, 0, 0); STGA(0, 1, 0); STGA(0, 2, 0); STGA(0, 3, 0);
    #pragma unroll
    for (int j = 0; j < NBJ; ++j) STGB(0, j, 0);

    const int KT = K >> 6;
    for (int i = 0; i < KT; ++i) {
        const int  par = i & 1, np = par ^ 1;
        const int  nk  = (i + 1) << 6;
        const bool pre = (i + 1 < KT);
        const char* abase = lds + par * ABUF;
        const char* bbase = lds + par * BBUF;  // boff carries BBASE
        f16x8 av[4], bv[4];
        // ph0: stage pair 0, wait current tile, quadrant (mh0, ks0)
        if (pre) { STGA(np, 0, nk); STGB(np, 0, nk);
                   asm volatile("s_waitcnt vmcnt(2)" ::: "memory"); }
        else     { asm volatile("s_waitcnt vmcnt(0)" ::: "memory"); }
        asm volatile("s_barrier" ::: "memory");
        LDB(0); LDA4(0, 0); FMA16(0);
        // ph1: (mh1, ks0)
        if (pre) { STGA(np, 1, nk); STGB(np, 1, nk); }
        LDA4(1, 0); FMA16(1);
        // ph2: (mh0, ks1)
        if (pre) { STGA(np, 2, nk); STGB(np, 2, nk); }
        LDB(1); LDA4(0, 1); FMA16(0);
        // ph3: (mh1, ks1)
        if (pre) { STGA(np, 3, nk); STGB(np, 3, nk); }
        LDA4(1, 1); FMA16(1);
        asm volatile("s_barrier" ::: "memory");
    }
#undef STGA
#undef STGB
#undef LDB
#undef LDA4
#undef FMA16

    if constexpr (!LIN1ACT) {
        #pragma unroll
        for (int mi = 0; mi < MR; ++mi)
            #pragma unroll
            for (int ni = 0; ni < NR; ++ni) {
                const int gcol = n0 + wn * WCOLS + ni * 16 + fr;
                const float bc = bias[gcol];
                #pragma unroll
                for (int r = 0; r < 4; ++r) {
                    const int grow = m0 + wm * WROWS + mi * 16 + q * 4 + r;
                    float v = acc[mi][ni][r] + bc;
                    if constexpr (OUTM == 2) {
                        v += residual[(size_t)grow * ldc + gcol];
                        Cf[(size_t)grow * ldc + gcol] = v;
                    } else {
                        Cq[(size_t)grow * ldc + gcol] = f2h(v);
                    }
                }
            }
    } else {
        unsigned short* xch = (unsigned short*)lds;   // [256][128] fp16 = 64KB
        if (wn >= 2) {
            #pragma unroll
            for (int mi = 0; mi < MR; ++mi)
                #pragma unroll
                for (int ni = 0; ni < NR; ++ni) {
                    const int pc = (wn - 2) * 64 + ni * 16 + fr;
                    const float bg = bias[FFH + n0 + pc];
                    #pragma unroll
                    for (int r = 0; r < 4; ++r) {
                        const int row = wm * WROWS + mi * 16 + q * 4 + r;
                        xch[row * 128 + pc] =
                            f2h(fmaxf(acc[mi][ni][r] + bg, 0.f));
                    }
                }
        }
        __syncthreads();
        if (wn < 2) {
            #pragma unroll
            for (int mi = 0; mi < MR; ++mi)
                #pragma unroll
                for (int ni = 0; ni < NR; ++ni) {
                    const int pc = wn * 64 + ni * 16 + fr;
                    const float ba = bias[n0 + pc];
                    #pragma unroll
                    for (int r = 0; r < 4; ++r) {
                        const int row = wm * WROWS + mi * 16 + q * 4 + r;
                        const float a = acc[mi][ni][r] + ba;
                        const float o = a * h2f(xch[row * 128 + pc]);
                        Cq[(size_t)(m0 + row) * FFH + n0 + pc] = f2h(o);
                    }
                }
        }
    }
}

// ---------------------------------------------------------------------------
// fgemm5 — R13-validated 256-thr GEMM (out + lin2). BM=128 only: 4 waves
// (2x2), wave 64x64, acc[4][4]. A staged via gl2lds 2-slot dbuf (32 KB ->
// 3 blocks/CU). B direct-to-reg from fragment-linear weights. Full
// __syncthreads() per K-tile. OUTM=2: fp32 out + residual.
// ---------------------------------------------------------------------------
template <int OUTM, int BM>
__global__ __launch_bounds__(256, 3) void fgemm5(
    const unsigned short* __restrict__ A,
    const unsigned short* __restrict__ Bsw,
    const float* __restrict__ bias,
    const float* __restrict__ residual,
    float* __restrict__ Cf, unsigned short* __restrict__ Cq,
    int K, int lda, int ldc)
{
    constexpr int WROWS = BM / 2;          // 64
    constexpr int MR    = WROWS / 16;      // 4
    constexpr int MH    = MR / 4;          // 1
    constexpr int ASLAB = BM * 128;        // 16384
    constexpr int AEV   = ASLAB / 4096;    // 4
    __shared__ __align__(16) char lds[2 * ASLAB];

    const int t   = threadIdx.x;
    const int wid = t >> 6, L = t & 63;
    const int wm  = wid >> 1, wn = wid & 1;
    const int fr  = L & 15, q = L >> 4;
    const int m0  = blockIdx.y * BM;
    const int n0  = blockIdx.x * 128;
    const int KT32 = K >> 5;

    const int srow = t >> 3;
    const int sch  = (t & 7) ^ (srow & 7);
    const unsigned short* pA = A + (size_t)(m0 + srow) * lda + sch * 8;

    const int ct0 = (n0 + wn * 64) >> 4;
    const unsigned short* pB = Bsw + (size_t)ct0 * KT32 * 512 + L * 8;

    int aoff[MR];
    #pragma unroll
    for (int mi = 0; mi < MR; ++mi) {
        const int row = wm * WROWS + mi * 16 + fr;
        aoff[mi] = row * 128 + ((q ^ (row & 7)) << 4);
    }

    f32x4 acc[MR][4];
    #pragma unroll
    for (int i = 0; i < MR; ++i)
        #pragma unroll
        for (int j = 0; j < 4; ++j) acc[i][j] = (f32x4){0.f, 0.f, 0.f, 0.f};
    f16x8 av[4], b0[4], b1[4];

#define SGA(sl, ko) do {                                                      \
        _Pragma("unroll")                                                     \
        for (int j_ = 0; j_ < AEV; ++j_)                                      \
            gl2lds16(pA + (size_t)j_ * 32 * lda + (ko),                       \
                     lds + (sl) * ASLAB + j_ * 4096 + t * 16);                \
    } while (0)
#define LB(dst, kt) do {                                                      \
        _Pragma("unroll")                                                     \
        for (int n_ = 0; n_ < 4; ++n_)                                        \
            dst[n_] = *(const f16x8*)(pB + ((size_t)n_ * KT32 + (kt)) * 512); \
    } while (0)
#define RD4(sl, ks, mh) do {                                                  \
        const char* ab_ = lds + (sl) * ASLAB;                                 \
        _Pragma("unroll")                                                     \
        for (int r_ = 0; r_ < 4; ++r_)                                        \
            av[r_] = *(const f16x8*)(ab_ + (aoff[(mh) * 4 + r_] ^             \
                                            ((ks) * 64)));                    \
    } while (0)
#define MM16(mh, B) do {                                                      \
        __builtin_amdgcn_s_setprio(1);                                        \
        _Pragma("unroll")                                                     \
        for (int r_ = 0; r_ < 4; ++r_)                                        \
            _Pragma("unroll")                                                 \
            for (int n_ = 0; n_ < 4; ++n_)                                    \
                acc[(mh) * 4 + r_][n_] =                                      \
                    __builtin_amdgcn_mfma_f32_16x16x32_f16(                   \
                        av[r_], B[n_], acc[(mh) * 4 + r_][n_], 0, 0, 0);      \
        __builtin_amdgcn_s_setprio(0);                                        \
    } while (0)

    const int KTile = K >> 6;

    SGA(0, 0);
    LB(b0, 0);
    __syncthreads();

    for (int T = 0; T < KTile; ++T) {
        const int  s  = T & 1, ns = s ^ 1;
        const bool pre = (T + 1 < KTile);
        LB(b1, 2 * T + 1);
        if (pre) SGA(ns, (T + 1) << 6);
        RD4(s, 0, 0); MM16(0, b0);
        if constexpr (MH == 2) { RD4(s, 0, 1); MM16(1, b0); }
        if (pre) LB(b0, 2 * T + 2);
        RD4(s, 1, 0); MM16(0, b1);
        if constexpr (MH == 2) { RD4(s, 1, 1); MM16(1, b1); }
        __syncthreads();   // validated full drain
    }
#undef SGA
#undef LB
#undef RD4
#undef MM16

    #pragma unroll
    for (int mi = 0; mi < MR; ++mi)
        #pragma unroll
        for (int ni = 0; ni < 4; ++ni) {
            const int gcol = n0 + wn * 64 + ni * 16 + fr;
            const float bc = bias[gcol];
            #pragma unroll
            for (int r = 0; r < 4; ++r) {
                const int grow = m0 + wm * WROWS + mi * 16 + q * 4 + r;
                float v = acc[mi][ni][r] + bc;
                if constexpr (OUTM == 2) {
                    v += residual[(size_t)grow * ldc + gcol];
                    Cf[(size_t)grow * ldc + gcol] = v;
                } else {
                    Cq[(size_t)grow * ldc + gcol] = f2h(v);
                }
            }
        }
}

// ---------------------------------------------------------------------------
extern "C" void kernel_launch(void* const* d_in, const int* in_sizes, int n_in,
                              void* d_out, int out_size, void* d_ws, size_t ws_size,
                              hipStream_t stream)
{
    const float* hidden = (const float*)d_in[0];
    const float* qkv_w  = (const float*)d_in[2];
    const float* qkv_b  = (const float*)d_in[3];
    const float* out_w  = (const float*)d_in[4];
    const float* out_b  = (const float*)d_in[5];
    const float* key_w  = (const float*)d_in[7];
    const float* n1g    = (const float*)d_in[8];
    const float* n1b    = (const float*)d_in[9];
    const float* n2g    = (const float*)d_in[10];
    const float* n2b    = (const float*)d_in[11];
    const float* l1w    = (const float*)d_in[12];
    const float* l1b    = (const float*)d_in[13];
    const float* l2w    = (const float*)d_in[14];
    const float* l2b    = (const float*)d_in[15];
    float* out = (float*)d_out;
    char*  wsb = (char*)d_ws;

    const size_t MB = 1u << 20;
    unsigned short* h16   = (unsigned short*)wsb;               // 16 MB
    unsigned short* kv16  = (unsigned short*)(wsb + 16 * MB);   // 32 MB
    unsigned short* act16 = (unsigned short*)(wsb + 16 * MB);   // overlay
    unsigned short* vq    = (unsigned short*)(wsb + 48 * MB);   // 16 MB
    unsigned short* wkv16 = (unsigned short*)(wsb + 64 * MB);   // 4 MB row-major
    unsigned short* l116  = (unsigned short*)(wsb + 68 * MB);   // 8 MB row-major
    unsigned short* wo_sw = (unsigned short*)(wsb + 76 * MB);   // 2 MB frag
    unsigned short* l2_sw = (unsigned short*)(wsb + 78 * MB);   // 4 MB frag
    float*          gk    = (float*)(wsb + 82 * MB);            // 32 KB
    float*          pm    = (float*)(wsb + 83 * MB);            // 128 KB
    float*          pl    = (float*)(wsb + 83 * MB + 131072);
    float*          ps    = (float*)(wsb + 83 * MB + 262144);

    // 0. weights -> fp16 (wkv/l1 row-major; wo/l2 fragment-linear)
    wcast2<<<4608, 256, 0, stream>>>(
        qkv_w + (size_t)DM * DM, l1w, out_w, l2w,
        wkv16, l116, wo_sw, l2_sw);

    // 1. h1 = LN1(hidden) -> fp16
    ln_f16<<<M_TOT, 256, 0, stream>>>(hidden, n1g, n1b, h16);

    // 2. kv16 = fp16( h1 @ Wkv^T + b )  (ldc 2048), 256 blocks
    fgemm2<false, 0, 256, 2><<<dim3(8, 32), 512, 0, stream>>>(
        h16, wkv16, qkv_b + DM, nullptr, nullptr, kv16, 1024, 1024, 2048);

    // 3. global_key (partial + merge)
    attn_part<<<512, 256, 0, stream>>>(kv16, key_w, pm, pl, ps);
    attn_merge<<<128, 64, 0, stream>>>(pm, pl, ps, gk);

    // 4. vq = fp16(v * gk)
    vscale_f16<<<M_TOT, 256, 0, stream>>>(kv16, gk, vq);

    // 5. hidden2 = hidden + vq @ out_w^T + out_b -> d_out, 512 blocks (2/CU)
    fgemm5<2, 128><<<dim3(8, 64), 256, 0, stream>>>(
        vq, wo_sw, out_b, hidden, out, nullptr, 1024, 1024, 1024);

    // 6. h2 = LN2(hidden2) -> fp16
    ln_f16<<<M_TOT, 256, 0, stream>>>(out, n2g, n2b, h16);

    // 7. act16 = fp16( (h2@W_a^T+b_a) * relu(h2@W_g^T+b_g) ), 512 blocks
    fgemm2<true, 0, 256, 2><<<dim3(16, 32), 512, 0, stream>>>(
        h16, l116, l1b, nullptr, nullptr, act16, 1024, 1024, 0);

    // 8. out = hidden2 + act @ l2w^T + l2b (in-place residual), 512 blocks
    fgemm5<2, 128><<<dim3(8, 64), 256, 0, stream>>>(
        act16, l2_sw, l2b, out, out, nullptr, 2048, 2048, 1024);
}

// Round 10
// 345.507 us; speedup vs baseline: 1.0982x; 1.0982x over previous
//
#include <hip/hip_runtime.h>
#include <math.h>

// ---------------------------------------------------------------------------
// Fastformer encoder layer — Round 17: exact R9 restore (measured best).
//
// R16 post-mortem: fgemm2 kv/lin1 reproduced (lin1 72.7 us, session best)
// but total regressed 346.6 -> 379.4. Only out/lin2 (fgemm5 B-direct) and
// wcast changed vs R9 => fgemm5-BM128 out/lin2 is ~30 us SLOWER than R9's
// fgemm2-BN128: B-direct loads drain under the per-tile __syncthreads and
// the B fragment stream re-fetches per m-block with no LDS amortization.
// The "validated faster" claim was inference from R13's (slower) total —
// never isolated. Reverting to the one configuration where every kernel
// was measured together at the session-best total:
//  * fgemm2 BN=256/WM=2: kv (dim3(8,32)), lin1 fused a*relu(g) (dim3(16,32))
//  * fgemm2 BN=128/WM=4: out, lin2 (dim3(8,32), 96KB LDS)
//  * wcast: all-row-major stream cast (coalesced read+write)
//  * no XCD swizzle (R14: B-replication across private L2s, FETCH +36%)
// ws: h16@0 | kv16/act16@16M | vq@48M | fp16 weights@64M | gk@82M | attn@83M
// ---------------------------------------------------------------------------

#define DM     1024
#define FFH    2048
#define M_TOT  8192

typedef _Float16 f16x8 __attribute__((ext_vector_type(8)));
typedef float    f32x4 __attribute__((ext_vector_type(4)));

__device__ __forceinline__ void gl2lds16(const void* g, void* l) {
    __builtin_amdgcn_global_load_lds(
        (const __attribute__((address_space(1))) void*)g,
        (__attribute__((address_space(3))) void*)l, 16, 0, 0);
}
__device__ __forceinline__ unsigned short f2h(float x) {
    union { _Float16 h; unsigned short u; } c;
    c.h = (_Float16)x;
    return c.u;
}
__device__ __forceinline__ float h2f(unsigned short u) {
    union { unsigned short u; _Float16 h; } c;
    c.u = u;
    return (float)c.h;
}

// ---------------------------------------------------------------------------
// weight cast fp32 -> fp16, plain row-major, fully coalesced (R9-validated).
// ---------------------------------------------------------------------------
__global__ __launch_bounds__(256) void wcast(
    const float* __restrict__ s0, const float* __restrict__ s1,
    const float* __restrict__ s2, const float* __restrict__ s3,
    unsigned short* __restrict__ d0, unsigned short* __restrict__ d1,
    unsigned short* __restrict__ d2, unsigned short* __restrict__ d3)
{
    int i = blockIdx.x * 256 + threadIdx.x;
    const float* s; unsigned short* d;
    if      (i < 262144) {               s = s0; d = d0; }
    else if (i < 393216) { i -= 262144;  s = s1; d = d1; }
    else if (i < 917504) { i -= 393216;  s = s2; d = d2; }
    else                 { i -= 917504;  s = s3; d = d3; }
    const float4 v0 = ((const float4*)(s + (size_t)i * 8))[0];
    const float4 v1 = ((const float4*)(s + (size_t)i * 8))[1];
    ushort4 h0, h1;
    h0.x = f2h(v0.x); h0.y = f2h(v0.y); h0.z = f2h(v0.z); h0.w = f2h(v0.w);
    h1.x = f2h(v1.x); h1.y = f2h(v1.y); h1.z = f2h(v1.z); h1.w = f2h(v1.w);
    unsigned short* dst = d + (size_t)i * 8;
    *(ushort4*)dst       = h0;
    *(ushort4*)(dst + 4) = h1;
}

// ---------------------------------------------------------------------------
// LayerNorm -> fp16. One block/row, one float4/thread.
// ---------------------------------------------------------------------------
__global__ __launch_bounds__(256) void ln_f16(
    const float* __restrict__ x, const float* __restrict__ g,
    const float* __restrict__ b, unsigned short* __restrict__ y)
{
    const int row = blockIdx.x;
    const int t   = threadIdx.x;
    const float4 v = ((const float4*)(x + (size_t)row * DM))[t];

    float s  = v.x + v.y + v.z + v.w;
    float ss = v.x * v.x + v.y * v.y + v.z * v.z + v.w * v.w;
    #pragma unroll
    for (int off = 32; off > 0; off >>= 1) {
        s  += __shfl_xor(s, off);
        ss += __shfl_xor(ss, off);
    }
    __shared__ float sm[8];
    const int wave = t >> 6;
    if ((t & 63) == 0) { sm[wave * 2] = s; sm[wave * 2 + 1] = ss; }
    __syncthreads();
    s  = sm[0] + sm[2] + sm[4] + sm[6];
    ss = sm[1] + sm[3] + sm[5] + sm[7];

    const float mu  = s * (1.0f / DM);
    const float var = ss * (1.0f / DM) - mu * mu;
    const float r   = rsqrtf(var + 1e-5f);

    const float4 gv = ((const float4*)g)[t];
    const float4 bv = ((const float4*)b)[t];
    ushort4 o;
    o.x = f2h((v.x - mu) * r * gv.x + bv.x);
    o.y = f2h((v.y - mu) * r * gv.y + bv.y);
    o.z = f2h((v.z - mu) * r * gv.z + bv.z);
    o.w = f2h((v.w - mu) * r * gv.w + bv.w);
    ((ushort4*)(y + (size_t)row * DM))[t] = o;
}

// ---------------------------------------------------------------------------
// attention partial pass + merge (verified R4-R16, unchanged).
// ---------------------------------------------------------------------------
__global__ __launch_bounds__(256) void attn_part(
    const unsigned short* __restrict__ kv, const float* __restrict__ kw,
    float* __restrict__ pm, float* __restrict__ pl, float* __restrict__ ps)
{
    const int blk = blockIdx.x;
    const int bh = blk >> 2, qt = blk & 3;
    const int b = bh >> 4, h = bh & 15;
    const int t = threadIdx.x, e = t & 63, w = t >> 6;
    const int nbase = qt * 256 + w * 64;
    const unsigned short* kp =
        kv + (size_t)b * 1024 * 2048 + (size_t)nbase * 2048 + h * 64 + e;
    const float* kwr = kw + h * 1024 + nbase;

    float m = -1e30f, l = 0.f, s = 0.f;
    #pragma unroll 4
    for (int i = 0; i < 64; ++i) {
        const float kval = h2f(kp[(size_t)i * 2048]);
        const float x    = kval * kwr[i] * 0.125f;
        const float nm   = fmaxf(m, x);
        const float c    = __expf(m - nm);
        const float ex   = __expf(x - nm);
        l = l * c + ex;
        s = s * c + ex * kval;
        m = nm;
    }
    __shared__ float sm[3][256];
    sm[0][t] = m; sm[1][t] = l; sm[2][t] = s;
    __syncthreads();
    if (t < 64) {
        #pragma unroll
        for (int ww = 1; ww < 4; ++ww) {
            const float m2 = sm[0][ww * 64 + e];
            const float l2 = sm[1][ww * 64 + e];
            const float s2 = sm[2][ww * 64 + e];
            const float nm = fmaxf(m, m2);
            const float c1 = __expf(m - nm);
            const float c2 = __expf(m2 - nm);
            l = l * c1 + l2 * c2;
            s = s * c1 + s2 * c2;
            m = nm;
        }
        const int o = blk * 64 + e;
        pm[o] = m; pl[o] = l; ps[o] = s;
    }
}

__global__ __launch_bounds__(64) void attn_merge(
    const float* __restrict__ pm, const float* __restrict__ pl,
    const float* __restrict__ ps, float* __restrict__ gk)
{
    const int bh = blockIdx.x, e = threadIdx.x;
    const int b = bh >> 4, h = bh & 15;
    int o = bh * 4 * 64 + e;
    float m = pm[o], l = pl[o], s = ps[o];
    #pragma unroll
    for (int qt = 1; qt < 4; ++qt) {
        o += 64;
        const float m2 = pm[o], l2 = pl[o], s2 = ps[o];
        const float nm = fmaxf(m, m2);
        const float c1 = __expf(m - nm);
        const float c2 = __expf(m2 - nm);
        l = l * c1 + l2 * c2;
        s = s * c1 + s2 * c2;
        m = nm;
    }
    gk[(size_t)b * DM + h * 64 + e] = s / l;
}

// ---------------------------------------------------------------------------
// v-scale: vq[m][d] = fp16( v16[m][d] * gk[batch][d] ).
// ---------------------------------------------------------------------------
__global__ __launch_bounds__(256) void vscale_f16(
    const unsigned short* __restrict__ kv, const float* __restrict__ gk,
    unsigned short* __restrict__ vq)
{
    const int m = blockIdx.x;
    const int t = threadIdx.x;
    const int b = m >> 10;
    const ushort4 v4 = *(const ushort4*)(kv + (size_t)m * 2048 + 1024 + t * 4);
    const float4  s4 = *(const float4*)(gk + b * DM + t * 4);
    ushort4 o;
    o.x = f2h(h2f(v4.x) * s4.x);
    o.y = f2h(h2f(v4.y) * s4.y);
    o.z = f2h(h2f(v4.z) * s4.z);
    o.w = f2h(h2f(v4.w) * s4.w);
    *(ushort4*)(vq + (size_t)m * DM + t * 4) = o;
}

// ---------------------------------------------------------------------------
// fp16 MFMA GEMM (R9-validated, session-best). 512 thr = 8 waves, 256-row
// block tile.
//   BN=256, WM=2: waves 2x4, per-wave 128x64, acc[8][4]; LDS 128KB.
//   BN=128, WM=4: waves 4x2, per-wave  64x64, acc[4][4]; LDS  96KB.
// A[M][K], W[N][K] row-major fp16; C = A@W^T (+bias [+residual]).
// A,B staged via gl2lds (validated 128B-row XOR layout). Counted vmcnt over
// the gl2lds-only VMEM stream. 4-phase interleave per K-tile, 2 barriers.
// LIN1ACT: block covers 128 product cols; B rows = {a: n0..+127,
// g: FFH+n0..+127}; epilogue fuses a*relu(g) via LDS xch.
// OUTM: 0 fp16 out, 2 fp32 out + residual.
// ---------------------------------------------------------------------------
template <bool LIN1ACT, int OUTM, int BN, int WM>
__global__ __launch_bounds__(512, 2) void fgemm2(
    const unsigned short* __restrict__ A,
    const unsigned short* __restrict__ W,
    const float* __restrict__ bias,
    const float* __restrict__ residual,
    float* __restrict__ Cf, unsigned short* __restrict__ Cq,
    int K, int lda, int ldc)
{
    constexpr int WN    = 8 / WM;
    constexpr int WROWS = 256 / WM;
    constexpr int WCOLS = BN / WN;
    constexpr int MR    = WROWS / 16;      // 8 (BN=256) or 4 (BN=128)
    constexpr int NR    = WCOLS / 16;      // 4
    static_assert(NR == 4, "NR must be 4");
    constexpr int NBJ   = BN / 64;         // B stage issues per K-tile
    constexpr int ABUF  = 32768;           // bytes per A stage (256x64 fp16)
    constexpr int BBUF  = BN * 128;        // bytes per B stage
    constexpr int BBASE = 2 * ABUF;

    __shared__ __align__(16) char lds[BBASE + 2 * BBUF];

    const int t   = threadIdx.x;
    const int wid = t >> 6, L = t & 63;
    const int wm  = wid % WM, wn = wid / WM;
    const int fr  = L & 15,  q  = L >> 4;
    const int m0  = blockIdx.y * 256;
    const int n0  = blockIdx.x * (LIN1ACT ? 128 : BN);

    // staging: chunk c = t + j*512 -> row c>>3, slot c&7 holds source chunk
    // (c&7)^(row&7). rows advance by 64 per j (low 3 bits invariant).
    const int srow = t >> 3;
    const int sch  = (t & 7) ^ (srow & 7);
    const unsigned short* pA  = A + (size_t)(m0 + srow) * lda + sch * 8;
    const unsigned short* pBs = W + (size_t)srow * K + sch * 8;
    size_t bro[4];
    #pragma unroll
    for (int j = 0; j < NBJ; ++j) {
        const int br = LIN1ACT ? ((j < 2) ? (n0 + 64 * j)
                                          : (FFH + n0 + 64 * (j - 2)))
                               : (n0 + 64 * j);
        bro[j] = (size_t)br * K;
    }

    // fragment read offsets (ks0; ks1 = ^64)
    int aoff[MR], boff[NR];
    #pragma unroll
    for (int mi = 0; mi < MR; ++mi) {
        const int row = wm * WROWS + mi * 16 + fr;
        aoff[mi] = row * 128 + ((q ^ (row & 7)) << 4);
    }
    #pragma unroll
    for (int ni = 0; ni < NR; ++ni) {
        const int col = wn * WCOLS + ni * 16 + fr;
        boff[ni] = BBASE + col * 128 + ((q ^ (col & 7)) << 4);
    }

    f32x4 acc[MR][NR];
    #pragma unroll
    for (int i = 0; i < MR; ++i)
        #pragma unroll
        for (int j = 0; j < NR; ++j) acc[i][j] = (f32x4){0.f, 0.f, 0.f, 0.f};

#define STGA(par, j, koff) gl2lds16(pA + (size_t)(j) * 64 * lda + (koff),     \
                                    lds + (par) * ABUF + t * 16 + (j) * 8192)
#define STGB(par, j, koff) gl2lds16(pBs + bro[j] + (koff),                    \
                                    lds + BBASE + (par) * BBUF + t * 16 +     \
                                    (j) * 8192)
#define LDB(ks) {                                                             \
    _Pragma("unroll")                                                         \
    for (int ni = 0; ni < 4; ++ni)                                            \
        bv[ni] = *(const f16x8*)(bbase + (boff[ni] ^ ((ks) * 64))); }
#define LDA4(mh, ks) {                                                        \
    _Pragma("unroll")                                                         \
    for (int r = 0; r < 4; ++r)                                               \
        av[r] = *(const f16x8*)(abase + (aoff[(mh) * 4 + r] ^ ((ks) * 64))); }
#define FMA16(mh) {                                                           \
    __builtin_amdgcn_s_setprio(1);                                            \
    _Pragma("unroll")                                                         \
    for (int r = 0; r < 4; ++r)                                               \
        _Pragma("unroll")                                                     \
        for (int ni = 0; ni < 4; ++ni)                                        \
            acc[(mh) * 4 + r][ni] = __builtin_amdgcn_mfma_f32_16x16x32_f16(   \
                av[r], bv[ni], acc[(mh) * 4 + r][ni], 0, 0, 0);               \
    __builtin_amdgcn_s_setprio(0); }

    // prologue: full tile 0 into parity 0
    STGA(0, 0, 0); STGA(0, 1, 0); STGA(0, 2, 0); STGA(0, 3, 0);
    #pragma unroll
    for (int j = 0; j < NBJ; ++j) STGB(0, j, 0);

    const int KT = K >> 6;
    for (int i = 0; i < KT; ++i) {
        const int  par = i & 1, np = par ^ 1;
        const int  nk  = (i + 1) << 6;         // next tile k offset (halves)
        const bool pre = (i + 1 < KT);
        const char* abase = lds + par * ABUF;
        const char* bbase = lds + par * BBUF;  // boff carries BBASE
        f16x8 av[4], bv[4];
        if constexpr (MR == 8) {
            // ph0: stage pair 0, wait current tile, quadrant (mh0, ks0)
            if (pre) { STGA(np, 0, nk); STGB(np, 0, nk);
                       asm volatile("s_waitcnt vmcnt(2)" ::: "memory"); }
            else     { asm volatile("s_waitcnt vmcnt(0)" ::: "memory"); }
            asm volatile("s_barrier" ::: "memory");
            LDB(0); LDA4(0, 0); FMA16(0);
            // ph1: (mh1, ks0)
            if (pre) { STGA(np, 1, nk); STGB(np, 1, nk); }
            LDA4(1, 0); FMA16(1);
            // ph2: (mh0, ks1)
            if (pre) { STGA(np, 2, nk); STGB(np, 2, nk); }
            LDB(1); LDA4(0, 1); FMA16(0);
            // ph3: (mh1, ks1)
            if (pre) { STGA(np, 3, nk); STGB(np, 3, nk); }
            LDA4(1, 1); FMA16(1);
            asm volatile("s_barrier" ::: "memory");
        } else {
            // ph0: 3 stage issues, wait current, ks0
            if (pre) { STGA(np, 0, nk); STGB(np, 0, nk); STGA(np, 2, nk);
                       asm volatile("s_waitcnt vmcnt(3)" ::: "memory"); }
            else     { asm volatile("s_waitcnt vmcnt(0)" ::: "memory"); }
            asm volatile("s_barrier" ::: "memory");
            LDB(0); LDA4(0, 0); FMA16(0);
            // ph1: remaining stages, ks1
            if (pre) { STGA(np, 1, nk); STGB(np, 1, nk); STGA(np, 3, nk); }
            LDB(1); LDA4(0, 1); FMA16(0);
            asm volatile("s_barrier" ::: "memory");
        }
    }
#undef STGA
#undef STGB
#undef LDB
#undef LDA4
#undef FMA16

    if constexpr (!LIN1ACT) {
        #pragma unroll
        for (int mi = 0; mi < MR; ++mi)
            #pragma unroll
            for (int ni = 0; ni < NR; ++ni) {
                const int gcol = n0 + wn * WCOLS + ni * 16 + fr;
                const float bc = bias[gcol];
                #pragma unroll
                for (int r = 0; r < 4; ++r) {
                    const int grow = m0 + wm * WROWS + mi * 16 + q * 4 + r;
                    float v = acc[mi][ni][r] + bc;
                    if constexpr (OUTM == 2) {
                        v += residual[(size_t)grow * ldc + gcol];
                        Cf[(size_t)grow * ldc + gcol] = v;
                    } else {
                        Cq[(size_t)grow * ldc + gcol] = f2h(v);
                    }
                }
            }
    } else {
        // a*relu(g) fuse: waves wn>=2 hold g (staged cols 128..255), push
        // relu(g) through LDS; waves wn<2 hold a, multiply and store.
        unsigned short* xch = (unsigned short*)lds;   // [256][128] fp16 = 64KB
        if (wn >= 2) {
            #pragma unroll
            for (int mi = 0; mi < MR; ++mi)
                #pragma unroll
                for (int ni = 0; ni < NR; ++ni) {
                    const int pc = (wn - 2) * 64 + ni * 16 + fr;
                    const float bg = bias[FFH + n0 + pc];
                    #pragma unroll
                    for (int r = 0; r < 4; ++r) {
                        const int row = wm * WROWS + mi * 16 + q * 4 + r;
                        xch[row * 128 + pc] =
                            f2h(fmaxf(acc[mi][ni][r] + bg, 0.f));
                    }
                }
        }
        __syncthreads();
        if (wn < 2) {
            #pragma unroll
            for (int mi = 0; mi < MR; ++mi)
                #pragma unroll
                for (int ni = 0; ni < NR; ++ni) {
                    const int pc = wn * 64 + ni * 16 + fr;
                    const float ba = bias[n0 + pc];
                    #pragma unroll
                    for (int r = 0; r < 4; ++r) {
                        const int row = wm * WROWS + mi * 16 + q * 4 + r;
                        const float a = acc[mi][ni][r] + ba;
                        const float o = a * h2f(xch[row * 128 + pc]);
                        Cq[(size_t)(m0 + row) * FFH + n0 + pc] = f2h(o);
                    }
                }
        }
    }
}

// ---------------------------------------------------------------------------
extern "C" void kernel_launch(void* const* d_in, const int* in_sizes, int n_in,
                              void* d_out, int out_size, void* d_ws, size_t ws_size,
                              hipStream_t stream)
{
    const float* hidden = (const float*)d_in[0];
    const float* qkv_w  = (const float*)d_in[2];
    const float* qkv_b  = (const float*)d_in[3];
    const float* out_w  = (const float*)d_in[4];
    const float* out_b  = (const float*)d_in[5];
    const float* key_w  = (const float*)d_in[7];
    const float* n1g    = (const float*)d_in[8];
    const float* n1b    = (const float*)d_in[9];
    const float* n2g    = (const float*)d_in[10];
    const float* n2b    = (const float*)d_in[11];
    const float* l1w    = (const float*)d_in[12];
    const float* l1b    = (const float*)d_in[13];
    const float* l2w    = (const float*)d_in[14];
    const float* l2b    = (const float*)d_in[15];
    float* out = (float*)d_out;
    char*  wsb = (char*)d_ws;

    const size_t MB = 1u << 20;
    unsigned short* h16   = (unsigned short*)wsb;               // 16 MB
    unsigned short* kv16  = (unsigned short*)(wsb + 16 * MB);   // 32 MB
    unsigned short* act16 = (unsigned short*)(wsb + 16 * MB);   // overlay
    unsigned short* vq    = (unsigned short*)(wsb + 48 * MB);   // 16 MB
    unsigned short* wkv16 = (unsigned short*)(wsb + 64 * MB);   // 4 MB
    unsigned short* wo16  = (unsigned short*)(wsb + 68 * MB);   // 2 MB
    unsigned short* l116  = (unsigned short*)(wsb + 70 * MB);   // 8 MB
    unsigned short* l216  = (unsigned short*)(wsb + 78 * MB);   // 4 MB
    float*          gk    = (float*)(wsb + 82 * MB);            // 32 KB
    float*          pm    = (float*)(wsb + 83 * MB);            // 128 KB
    float*          pl    = (float*)(wsb + 83 * MB + 131072);
    float*          ps    = (float*)(wsb + 83 * MB + 262144);

    // 0. weights -> fp16, plain row-major
    wcast<<<4608, 256, 0, stream>>>(
        qkv_w + (size_t)DM * DM, out_w, l1w, l2w,
        wkv16, wo16, l116, l216);

    // 1. h1 = LN1(hidden) -> fp16
    ln_f16<<<M_TOT, 256, 0, stream>>>(hidden, n1g, n1b, h16);

    // 2. kv16 = fp16( h1 @ Wkv^T + b )  (ldc 2048), 256 blocks
    fgemm2<false, 0, 256, 2><<<dim3(8, 32), 512, 0, stream>>>(
        h16, wkv16, qkv_b + DM, nullptr, nullptr, kv16, 1024, 1024, 2048);

    // 3. global_key (partial + merge)
    attn_part<<<512, 256, 0, stream>>>(kv16, key_w, pm, pl, ps);
    attn_merge<<<128, 64, 0, stream>>>(pm, pl, ps, gk);

    // 4. vq = fp16(v * gk)
    vscale_f16<<<M_TOT, 256, 0, stream>>>(kv16, gk, vq);

    // 5. hidden2 = hidden + vq @ out_w^T + out_b -> d_out, 256 blocks
    fgemm2<false, 2, 128, 4><<<dim3(8, 32), 512, 0, stream>>>(
        vq, wo16, out_b, hidden, out, nullptr, 1024, 1024, 1024);

    // 6. h2 = LN2(hidden2) -> fp16
    ln_f16<<<M_TOT, 256, 0, stream>>>(out, n2g, n2b, h16);

    // 7. act16 = fp16( (h2@W_a^T+b_a) * relu(h2@W_g^T+b_g) ), 512 blocks
    fgemm2<true, 0, 256, 2><<<dim3(16, 32), 512, 0, stream>>>(
        h16, l116, l1b, nullptr, nullptr, act16, 1024, 1024, 0);

    // 8. out = hidden2 + act @ l2w^T + l2b (in-place residual), 256 blocks
    fgemm2<false, 2, 128, 4><<<dim3(8, 32), 512, 0, stream>>>(
        act16, l216, l2b, out, out, nullptr, 2048, 2048, 1024);
}